// Round 1
// baseline (6741.953 us; speedup 1.0000x reference)
//
#include <hip/hip_runtime.h>
#include <math.h>

#define N_NODES 100000
#define N_EDGES 1600000
#define DIM     128
#define NPOOL0  50000
#define NPOOL1  25000
#define NGRAPH  64

__device__ __forceinline__ float lrelu(float v) { return v > 0.f ? v : 0.01f * v; }

// float atomic max via signed/unsigned int ordering trick (valid for mixed signs, -inf init)
__device__ __forceinline__ void atomicMaxF(float* addr, float val) {
    if (val >= 0.f) atomicMax((int*)addr, __float_as_int(val));
    else            atomicMin((unsigned int*)addr, __float_as_uint(val));
}

// ---------------- fills ----------------
__global__ __launch_bounds__(256) void fill_f32(float* __restrict__ p, int n, float v) {
    int i = blockIdx.x * 256 + threadIdx.x;
    if (i < n) p[i] = v;
}
__global__ __launch_bounds__(256) void fill_i32(int* __restrict__ p, int n, int v) {
    int i = blockIdx.x * 256 + threadIdx.x;
    if (i < n) p[i] = v;
}

// ---------------- fused 2-layer MLP: Y = lrelu((X@W1^T+b1)*g+be) @ W2^T + b2 ----------------
// X:[R][KIN], W1:[HID][KIN], W2:[128][HID], Y:[R][128]
template<int KIN, int HID>
__global__ __launch_bounds__(256) void mlp_fused(
        const float* __restrict__ X, int R,
        const float* __restrict__ W1, const float* __restrict__ B1,
        const float* __restrict__ G1, const float* __restrict__ BE1,
        const float* __restrict__ W2, const float* __restrict__ B2,
        float* __restrict__ Y)
{
    constexpr int TR = 16;
    constexpr int WSC = (HID > 128) ? HID : 128;
    __shared__ float xs[TR][KIN + 4];
    __shared__ float ts[TR][HID + 4];
    __shared__ float ws[32 * WSC];

    const int tid = threadIdx.x;
    const int ty = tid >> 4;        // row within tile [0,16)
    const int tx = tid & 15;        // col group [0,16)
    const int r0 = blockIdx.x * TR;

    // stage x tile (zero-fill OOB rows)
    {
        const int r = r0 + ty;
        const int cb = tx * (KIN / 16);
        if (r < R) {
            #pragma unroll
            for (int q = 0; q < KIN / 16; q += 4)
                *(float4*)&xs[ty][cb + q] = *(const float4*)&X[(size_t)r * KIN + cb + q];
        } else {
            #pragma unroll
            for (int q = 0; q < KIN / 16; q += 4)
                *(float4*)&xs[ty][cb + q] = float4{0.f, 0.f, 0.f, 0.f};
        }
    }

    // ---- layer 1 ----
    constexpr int NJ1 = HID / 16;
    float acc[NJ1];
    #pragma unroll
    for (int j = 0; j < NJ1; ++j) acc[j] = 0.f;

    for (int kc = 0; kc < KIN; kc += 32) {
        __syncthreads();
        // stage W1 chunk transposed: ws[kk][c] = W1[c][kc+kk]
        for (int lin = tid; lin < HID * 8; lin += 256) {
            const int c = lin >> 3, q = lin & 7;
            float4 v = *(const float4*)&W1[(size_t)c * KIN + kc + q * 4];
            ws[(q * 4 + 0) * HID + c] = v.x;
            ws[(q * 4 + 1) * HID + c] = v.y;
            ws[(q * 4 + 2) * HID + c] = v.z;
            ws[(q * 4 + 3) * HID + c] = v.w;
        }
        __syncthreads();
        #pragma unroll
        for (int kk = 0; kk < 32; ++kk) {
            const float xv = xs[ty][kc + kk];
            #pragma unroll
            for (int j = 0; j < NJ1; ++j) acc[j] += xv * ws[kk * HID + tx + 16 * j];
        }
    }
    __syncthreads();
    #pragma unroll
    for (int j = 0; j < NJ1; ++j) {
        const int c = tx + 16 * j;
        const float v = (acc[j] + B1[c]) * G1[c] + BE1[c];
        ts[ty][c] = lrelu(v);
    }

    // ---- layer 2 ----
    float acc2[8];
    #pragma unroll
    for (int j = 0; j < 8; ++j) acc2[j] = 0.f;

    for (int kc = 0; kc < HID; kc += 32) {
        __syncthreads();
        for (int lin = tid; lin < 128 * 8; lin += 256) {
            const int c = lin >> 3, q = lin & 7;
            float4 v = *(const float4*)&W2[(size_t)c * HID + kc + q * 4];
            ws[(q * 4 + 0) * 128 + c] = v.x;
            ws[(q * 4 + 1) * 128 + c] = v.y;
            ws[(q * 4 + 2) * 128 + c] = v.z;
            ws[(q * 4 + 3) * 128 + c] = v.w;
        }
        __syncthreads();
        #pragma unroll
        for (int kk = 0; kk < 32; ++kk) {
            const float tv = ts[ty][kc + kk];
            #pragma unroll
            for (int j = 0; j < 8; ++j) acc2[j] += tv * ws[kk * 128 + tx + 16 * j];
        }
    }
    const int r = r0 + ty;
    if (r < R) {
        #pragma unroll
        for (int j = 0; j < 8; ++j) {
            const int c = tx + 16 * j;
            Y[(size_t)r * 128 + c] = acc2[j] + B2[c];
        }
    }
}

// ---------------- edge kernels ----------------
__global__ __launch_bounds__(256) void add_deg(const int* __restrict__ src, float* __restrict__ deg, int E) {
    int e = blockIdx.x * 256 + threadIdx.x;
    if (e < E) atomicAdd(&deg[src[e]], 1.0f);
}
__global__ __launch_bounds__(256) void rsqrt_ip(float* __restrict__ p, int n) {
    int i = blockIdx.x * 256 + threadIdx.x;
    if (i < n) p[i] = rsqrtf(p[i]);
}
// agg[i][d] = dis[i]^2 * H[i][d]   (self-loop term; also serves as accumulator init)
__global__ __launch_bounds__(256) void selfinit(const float* __restrict__ dis, const float* __restrict__ H,
                                                float* __restrict__ AGG, int total) {
    int idx = blockIdx.x * 256 + threadIdx.x;
    if (idx < total) {
        float d = dis[idx >> 7];
        AGG[idx] = d * d * H[idx];
    }
}
// 32 lanes per edge, float4 per lane: AGG[dst] += dis[s]*dis[t]*ea[e] * H[src]
__global__ __launch_bounds__(256) void scatter_edges(
        const int* __restrict__ src, const int* __restrict__ dst,
        const float* __restrict__ ea, const float* __restrict__ dis,
        const float* __restrict__ H, float* __restrict__ AGG, int E)
{
    int e = blockIdx.x * 8 + (threadIdx.x >> 5);
    if (e >= E) return;
    int lane = threadIdx.x & 31;
    int s = src[e], t = dst[e];
    float coeff = dis[s] * dis[t] * ea[e];
    float4 h = *(const float4*)&H[(size_t)s * DIM + lane * 4];
    float* o = &AGG[(size_t)t * DIM + lane * 4];
    atomicAdd(o + 0, coeff * h.x);
    atomicAdd(o + 1, coeff * h.y);
    atomicAdd(o + 2, coeff * h.z);
    atomicAdd(o + 3, coeff * h.w);
}
// src2[e]=c1[c0[ei0[e]]], dst2[e]=c1[c0[ei1[e]]], deg2[src2]+=1
__global__ __launch_bounds__(256) void edgemap(
        const int* __restrict__ ei0, const int* __restrict__ ei1,
        const int* __restrict__ c0, const int* __restrict__ c1,
        int* __restrict__ src2, int* __restrict__ dst2, float* __restrict__ deg2, int E)
{
    int e = blockIdx.x * 256 + threadIdx.x;
    if (e < E) {
        int s = c1[c0[ei0[e]]];
        int d = c1[c0[ei1[e]]];
        src2[e] = s;
        dst2[e] = d;
        atomicAdd(&deg2[s], 1.0f);
    }
}

// ---------------- pooling kernels ----------------
__global__ __launch_bounds__(256) void pool1(const float* __restrict__ agg, const float* __restrict__ x,
                                             const int* __restrict__ c0,
                                             float* __restrict__ px, float* __restrict__ ox, int total) {
    int idx = blockIdx.x * 256 + threadIdx.x;
    if (idx < total) {
        int i = idx >> 7, d = idx & 127;
        int c = c0[i];
        float xv = x[idx];
        float hv = agg[idx] + xv;         // residual h = mpnn0(x) + x
        atomicMaxF(&px[(size_t)c * DIM + d], lrelu(hv));
        atomicMaxF(&ox[(size_t)c * DIM + d], xv);
    }
}
__global__ __launch_bounds__(256) void h2k(const float* __restrict__ px, const float* __restrict__ ox,
                                           float* __restrict__ h2, int total) {
    int idx = blockIdx.x * 256 + threadIdx.x;
    if (idx < total) {
        float a = px[idx], b = ox[idx];
        a = (a == -INFINITY) ? 0.f : a;
        b = (b == -INFINITY) ? 0.f : b;
        h2[idx] = a + b;
    }
}
__global__ __launch_bounds__(256) void pool2(const float* __restrict__ h2, const int* __restrict__ c1,
                                             float* __restrict__ x2, int total) {
    int idx = blockIdx.x * 256 + threadIdx.x;
    if (idx < total) {
        int i = idx >> 7, d = idx & 127;
        atomicMaxF(&x2[(size_t)c1[i] * DIM + d], lrelu(h2[idx]));
    }
}
__global__ __launch_bounds__(256) void fixinf(float* __restrict__ p, int total) {
    int idx = blockIdx.x * 256 + threadIdx.x;
    if (idx < total && p[idx] == -INFINITY) p[idx] = 0.f;
}
__global__ __launch_bounds__(256) void segmax_i32(const int* __restrict__ map, const int* __restrict__ vals,
                                                  int* __restrict__ out, int n) {
    int i = blockIdx.x * 256 + threadIdx.x;
    if (i < n) atomicMax(&out[map[i]], vals[i]);
}
__global__ __launch_bounds__(256) void gpool(const float* __restrict__ agg2, const int* __restrict__ pb2,
                                             float* __restrict__ gmax, int total) {
    int idx = blockIdx.x * 256 + threadIdx.x;
    if (idx < total) {
        int i = idx >> 7, d = idx & 127;
        atomicMaxF(&gmax[(size_t)pb2[i] * DIM + d], lrelu(agg2[idx]));
    }
}

// ---------------- head: emb + concat + MLP + out ----------------
__global__ __launch_bounds__(128) void head(
        const float* __restrict__ gmax, const float* __restrict__ energy,
        const float* __restrict__ emb_w, const float* __restrict__ emb_b,
        const float* __restrict__ emb_g, const float* __restrict__ emb_be,
        const float* __restrict__ lw1, const float* __restrict__ lb1,
        const float* __restrict__ lg, const float* __restrict__ lbe,
        const float* __restrict__ lw2, const float* __restrict__ lb2,
        float* __restrict__ out)
{
    const int g = blockIdx.x;
    const int t = threadIdx.x;  // 128
    __shared__ float z[136];
    __shared__ float red[128];

    {
        float v = gmax[(size_t)g * DIM + t];
        z[t] = (v == -INFINITY) ? 0.f : v;
    }
    if (t < 8) {
        float s = 0.f;
        #pragma unroll
        for (int k = 0; k < 21; ++k) s += energy[g * 21 + k] * emb_w[t * 21 + k];
        s = (s + emb_b[t]) * emb_g[t] + emb_be[t];
        z[128 + t] = lrelu(s);
    }
    __syncthreads();
    float s = 0.f;
    #pragma unroll 8
    for (int k = 0; k < 136; ++k) s += z[k] * lw1[t * 136 + k];
    float z2 = lrelu((s + lb1[t]) * lg[t] + lbe[t]);
    red[t] = z2 * lw2[t];
    __syncthreads();
    if (t == 0) {
        float acc = lb2[0];
        for (int k = 0; k < 128; ++k) acc += red[k];
        out[g] = acc;
    }
}

extern "C" void kernel_launch(void* const* d_in, const int* in_sizes, int n_in,
                              void* d_out, int out_size, void* d_ws, size_t ws_size,
                              hipStream_t stream) {
    const float* x        = (const float*)d_in[0];
    const float* edge_attr= (const float*)d_in[1];
    const float* energy   = (const float*)d_in[2];
    const float* w0a = (const float*)d_in[3];
    const float* b0a = (const float*)d_in[4];
    const float* g0  = (const float*)d_in[5];
    const float* be0 = (const float*)d_in[6];
    const float* w0b = (const float*)d_in[7];
    const float* b0b = (const float*)d_in[8];
    // d_in[9..14]: dead mpnn_1 params
    const float* w2a = (const float*)d_in[15];
    const float* b2a = (const float*)d_in[16];
    const float* g2  = (const float*)d_in[17];
    const float* be2 = (const float*)d_in[18];
    const float* w2b = (const float*)d_in[19];
    const float* b2b = (const float*)d_in[20];
    const float* emb_w  = (const float*)d_in[21];
    const float* emb_b  = (const float*)d_in[22];
    const float* emb_g  = (const float*)d_in[23];
    const float* emb_be = (const float*)d_in[24];
    const float* lw1 = (const float*)d_in[25];
    const float* lb1 = (const float*)d_in[26];
    const float* lg  = (const float*)d_in[27];
    const float* lbe = (const float*)d_in[28];
    const float* lw2 = (const float*)d_in[29];
    const float* lb2 = (const float*)d_in[30];
    const int* ei0   = (const int*)d_in[31];
    const int* ei1   = ei0 + N_EDGES;
    const int* batch = (const int*)d_in[32];
    const int* c0    = (const int*)d_in[33];
    const int* c1    = (const int*)d_in[34];
    float* out = (float*)d_out;

    // workspace layout (region reuse; peak ~103.3 MB)
    char* ws = (char*)d_ws;
    float* h_mlp = (float*)(ws + 0);          // [N,128]       live: mlp0 .. scatter0
    float* px    = (float*)(ws + 0);          // [N0,128]      live: pool1 .. h2k
    float* ox    = (float*)(ws + 25600000);   // [N0,128]
    float* x2    = (float*)(ws + 0);          // [N1,128]      live: pool2 .. mlp2
    int*   src2  = (int*)(ws + 12800000);     // [E]
    int*   dst2  = (int*)(ws + 19200000);     // [E]
    float* hm2   = (float*)(ws + 25600000);   // [N1,128]      live: mlp2 .. scatter2
    float* agg0  = (float*)(ws + 51200000);   // [N,128]       live: selfinit .. pool1
    float* h2    = (float*)(ws + 51200000);   // [N0,128]      live: h2k .. pool2
    float* agg2  = (float*)(ws + 76800000);   // [N1,128]      live: selfinit2 .. gpool
    float* deg0  = (float*)(ws + 102400000);  // [N]  (becomes dis0)
    float* deg2  = (float*)(ws + 102800000);  // [N1] (becomes dis2)
    int*   pb    = (int*)(ws + 102900000);    // [N0]
    int*   pb2   = (int*)(ws + 103100000);    // [N1]
    float* gmax  = (float*)(ws + 103200000);  // [64,128]

    (void)in_sizes; (void)n_in; (void)out_size; (void)ws_size;

    // ---- mpnn0 ----
    fill_f32<<<(N_NODES + 255) / 256, 256, 0, stream>>>(deg0, N_NODES, 1.0f);
    mlp_fused<128, 128><<<(N_NODES + 15) / 16, 256, 0, stream>>>(x, N_NODES, w0a, b0a, g0, be0, w0b, b0b, h_mlp);
    add_deg<<<(N_EDGES + 255) / 256, 256, 0, stream>>>(ei0, deg0, N_EDGES);
    rsqrt_ip<<<(N_NODES + 255) / 256, 256, 0, stream>>>(deg0, N_NODES);
    selfinit<<<(N_NODES * DIM + 255) / 256, 256, 0, stream>>>(deg0, h_mlp, agg0, N_NODES * DIM);
    scatter_edges<<<(N_EDGES + 7) / 8, 256, 0, stream>>>(ei0, ei1, edge_attr, deg0, h_mlp, agg0, N_EDGES);

    // ---- pool 1 ----
    fill_f32<<<(NPOOL0 * DIM + 255) / 256, 256, 0, stream>>>(px, NPOOL0 * DIM, -INFINITY);
    fill_f32<<<(NPOOL0 * DIM + 255) / 256, 256, 0, stream>>>(ox, NPOOL0 * DIM, -INFINITY);
    pool1<<<(N_NODES * DIM + 255) / 256, 256, 0, stream>>>(agg0, x, c0, px, ox, N_NODES * DIM);
    fill_i32<<<(NPOOL0 + 255) / 256, 256, 0, stream>>>(pb, NPOOL0, 0);
    segmax_i32<<<(N_NODES + 255) / 256, 256, 0, stream>>>(c0, batch, pb, N_NODES);
    h2k<<<(NPOOL0 * DIM + 255) / 256, 256, 0, stream>>>(px, ox, h2, NPOOL0 * DIM);

    // ---- pool 2 ----
    fill_f32<<<(NPOOL1 * DIM + 255) / 256, 256, 0, stream>>>(x2, NPOOL1 * DIM, -INFINITY);
    pool2<<<(NPOOL0 * DIM + 255) / 256, 256, 0, stream>>>(h2, c1, x2, NPOOL0 * DIM);
    fixinf<<<(NPOOL1 * DIM + 255) / 256, 256, 0, stream>>>(x2, NPOOL1 * DIM);
    fill_i32<<<(NPOOL1 + 255) / 256, 256, 0, stream>>>(pb2, NPOOL1, 0);
    segmax_i32<<<(NPOOL0 + 255) / 256, 256, 0, stream>>>(c1, pb, pb2, NPOOL0);

    // ---- mpnn2 ----
    fill_f32<<<(NPOOL1 + 255) / 256, 256, 0, stream>>>(deg2, NPOOL1, 1.0f);
    edgemap<<<(N_EDGES + 255) / 256, 256, 0, stream>>>(ei0, ei1, c0, c1, src2, dst2, deg2, N_EDGES);
    rsqrt_ip<<<(NPOOL1 + 255) / 256, 256, 0, stream>>>(deg2, NPOOL1);
    mlp_fused<128, 256><<<(NPOOL1 + 15) / 16, 256, 0, stream>>>(x2, NPOOL1, w2a, b2a, g2, be2, w2b, b2b, hm2);
    selfinit<<<(NPOOL1 * DIM + 255) / 256, 256, 0, stream>>>(deg2, hm2, agg2, NPOOL1 * DIM);
    scatter_edges<<<(N_EDGES + 7) / 8, 256, 0, stream>>>(src2, dst2, edge_attr, deg2, hm2, agg2, N_EDGES);

    // ---- global pool + head ----
    fill_f32<<<(NGRAPH * DIM + 255) / 256, 256, 0, stream>>>(gmax, NGRAPH * DIM, -INFINITY);
    gpool<<<(NPOOL1 * DIM + 255) / 256, 256, 0, stream>>>(agg2, pb2, gmax, NPOOL1 * DIM);
    head<<<NGRAPH, 128, 0, stream>>>(gmax, energy, emb_w, emb_b, emb_g, emb_be,
                                     lw1, lb1, lg, lbe, lw2, lb2, out);
}

// Round 2
// 2190.178 us; speedup vs baseline: 3.0783x; 3.0783x over previous
//
#include <hip/hip_runtime.h>
#include <hip/hip_bf16.h>
#include <math.h>

#define N_NODES 100000
#define N_EDGES 1600000
#define DIM     128
#define NPOOL0  50000
#define NPOOL1  25000
#define NGRAPH  64

__device__ __forceinline__ float lrelu(float v) { return v > 0.f ? v : 0.01f * v; }

// float atomic max: signed-max for v>=0, unsigned-min for v<0. Monotone and
// correct for mixed signs with -inf init (see round-1: passed absmax 0.0).
__device__ __forceinline__ void atomicMaxF(float* addr, float val) {
    if (val >= 0.f) atomicMax((int*)addr, __float_as_int(val));
    else            atomicMin((unsigned int*)addr, __float_as_uint(val));
}

__device__ __forceinline__ float2 ld_bf16x2(const unsigned int* row, int lane) {
    unsigned int v = row[lane];
    float2 r;
    r.x = __uint_as_float(v << 16);
    r.y = __uint_as_float(v & 0xFFFF0000u);
    return r;
}

// ---------------- fills ----------------
__global__ __launch_bounds__(256) void fill_f32(float* __restrict__ p, int n, float v) {
    int i = blockIdx.x * 256 + threadIdx.x;
    if (i < n) p[i] = v;
}
__global__ __launch_bounds__(256) void fill_i32(int* __restrict__ p, int n, int v) {
    int i = blockIdx.x * 256 + threadIdx.x;
    if (i < n) p[i] = v;
}

// ---------------- fused 2-layer MLP: Y = lrelu((X@W1^T+b1)*g+be) @ W2^T + b2 ----------------
template<int KIN, int HID, typename OT>
__global__ __launch_bounds__(256) void mlp_fused(
        const float* __restrict__ X, int R,
        const float* __restrict__ W1, const float* __restrict__ B1,
        const float* __restrict__ G1, const float* __restrict__ BE1,
        const float* __restrict__ W2, const float* __restrict__ B2,
        OT* __restrict__ Y)
{
    constexpr int TR = 16;
    constexpr int WSC = (HID > 128) ? HID : 128;
    __shared__ float xs[TR][KIN + 4];
    __shared__ float ts[TR][HID + 4];
    __shared__ float ws[32 * WSC];

    const int tid = threadIdx.x;
    const int ty = tid >> 4;
    const int tx = tid & 15;
    const int r0 = blockIdx.x * TR;

    {
        const int r = r0 + ty;
        const int cb = tx * (KIN / 16);
        if (r < R) {
            #pragma unroll
            for (int q = 0; q < KIN / 16; q += 4)
                *(float4*)&xs[ty][cb + q] = *(const float4*)&X[(size_t)r * KIN + cb + q];
        } else {
            #pragma unroll
            for (int q = 0; q < KIN / 16; q += 4)
                *(float4*)&xs[ty][cb + q] = float4{0.f, 0.f, 0.f, 0.f};
        }
    }

    constexpr int NJ1 = HID / 16;
    float acc[NJ1];
    #pragma unroll
    for (int j = 0; j < NJ1; ++j) acc[j] = 0.f;

    for (int kc = 0; kc < KIN; kc += 32) {
        __syncthreads();
        for (int lin = tid; lin < HID * 8; lin += 256) {
            const int c = lin >> 3, q = lin & 7;
            float4 v = *(const float4*)&W1[(size_t)c * KIN + kc + q * 4];
            ws[(q * 4 + 0) * HID + c] = v.x;
            ws[(q * 4 + 1) * HID + c] = v.y;
            ws[(q * 4 + 2) * HID + c] = v.z;
            ws[(q * 4 + 3) * HID + c] = v.w;
        }
        __syncthreads();
        #pragma unroll
        for (int kk = 0; kk < 32; ++kk) {
            const float xv = xs[ty][kc + kk];
            #pragma unroll
            for (int j = 0; j < NJ1; ++j) acc[j] += xv * ws[kk * HID + tx + 16 * j];
        }
    }
    __syncthreads();
    #pragma unroll
    for (int j = 0; j < NJ1; ++j) {
        const int c = tx + 16 * j;
        const float v = (acc[j] + B1[c]) * G1[c] + BE1[c];
        ts[ty][c] = lrelu(v);
    }

    float acc2[8];
    #pragma unroll
    for (int j = 0; j < 8; ++j) acc2[j] = 0.f;

    for (int kc = 0; kc < HID; kc += 32) {
        __syncthreads();
        for (int lin = tid; lin < 128 * 8; lin += 256) {
            const int c = lin >> 3, q = lin & 7;
            float4 v = *(const float4*)&W2[(size_t)c * HID + kc + q * 4];
            ws[(q * 4 + 0) * 128 + c] = v.x;
            ws[(q * 4 + 1) * 128 + c] = v.y;
            ws[(q * 4 + 2) * 128 + c] = v.z;
            ws[(q * 4 + 3) * 128 + c] = v.w;
        }
        __syncthreads();
        #pragma unroll
        for (int kk = 0; kk < 32; ++kk) {
            const float tv = ts[ty][kc + kk];
            #pragma unroll
            for (int j = 0; j < 8; ++j) acc2[j] += tv * ws[kk * 128 + tx + 16 * j];
        }
    }
    const int r = r0 + ty;
    if (r < R) {
        #pragma unroll
        for (int j = 0; j < 8; ++j) {
            const int c = tx + 16 * j;
            const float v = acc2[j] + B2[c];
            if constexpr (sizeof(OT) == 2) Y[(size_t)r * 128 + c] = __float2bfloat16(v);
            else                           Y[(size_t)r * 128 + c] = v;
        }
    }
}

// ---------------- CSR build ----------------
// deg[src]+=1 (float, self-loop pre-init 1.0), cnt[dst]+=1 (int)
__global__ __launch_bounds__(256) void count0(const int* __restrict__ src, const int* __restrict__ dst,
                                              float* __restrict__ deg, int* __restrict__ cnt, int E) {
    int e = blockIdx.x * 256 + threadIdx.x;
    if (e < E) {
        atomicAdd(&deg[src[e]], 1.0f);
        atomicAdd(&cnt[dst[e]], 1);
    }
}
__global__ __launch_bounds__(256) void rsqrt_ip(float* __restrict__ p, int n) {
    int i = blockIdx.x * 256 + threadIdx.x;
    if (i < n) p[i] = rsqrtf(p[i]);
}
// 3-kernel exclusive scan of cnt -> offs
__global__ __launch_bounds__(256) void scan_blk(const int* __restrict__ cnt, int* __restrict__ offs,
                                                int* __restrict__ bsum, int n) {
    __shared__ int s[256];
    const int tid = threadIdx.x;
    const int i = blockIdx.x * 256 + tid;
    int v = (i < n) ? cnt[i] : 0;
    s[tid] = v;
    __syncthreads();
    #pragma unroll
    for (int d = 1; d < 256; d <<= 1) {
        int t = (tid >= d) ? s[tid - d] : 0;
        __syncthreads();
        s[tid] += t;
        __syncthreads();
    }
    if (i < n) offs[i] = s[tid] - v;         // exclusive within block
    if (tid == 255) bsum[blockIdx.x] = s[255];
}
__global__ __launch_bounds__(512) void scan_top(int* __restrict__ bsum, int nb) {
    __shared__ int s[512];
    const int tid = threadIdx.x;
    int v = (tid < nb) ? bsum[tid] : 0;
    s[tid] = v;
    __syncthreads();
    #pragma unroll
    for (int d = 1; d < 512; d <<= 1) {
        int t = (tid >= d) ? s[tid - d] : 0;
        __syncthreads();
        s[tid] += t;
        __syncthreads();
    }
    if (tid < nb) bsum[tid] = s[tid] - v;    // exclusive
}
__global__ __launch_bounds__(256) void scan_add(int* __restrict__ offs, const int* __restrict__ bsum,
                                                int* __restrict__ fill, int n) {
    int i = blockIdx.x * 256 + threadIdx.x;
    if (i < n) {
        int o = offs[i] + bsum[i >> 8];
        offs[i] = o;
        fill[i] = o;
    }
}
__global__ __launch_bounds__(256) void place(const int* __restrict__ dst, int* __restrict__ fill,
                                             int* __restrict__ csr, int E) {
    int e = blockIdx.x * 256 + threadIdx.x;
    if (e < E) {
        int pos = atomicAdd(&fill[dst[e]], 1);
        csr[pos] = e;
    }
}
// src2[e]=c1[c0[ei0[e]]], dst2[e]=c1[c0[ei1[e]]], deg2[src2]+=1, cnt2[dst2]+=1
__global__ __launch_bounds__(256) void edgemap(
        const int* __restrict__ ei0, const int* __restrict__ ei1,
        const int* __restrict__ c0, const int* __restrict__ c1,
        int* __restrict__ src2, int* __restrict__ dst2,
        float* __restrict__ deg2, int* __restrict__ cnt2, int E)
{
    int e = blockIdx.x * 256 + threadIdx.x;
    if (e < E) {
        int s = c1[c0[ei0[e]]];
        int d = c1[c0[ei1[e]]];
        src2[e] = s;
        dst2[e] = d;
        atomicAdd(&deg2[s], 1.0f);
        atomicAdd(&cnt2[d], 1);
    }
}

// ---------------- gather-reduce (one wave per dst node) ----------------
// mpnn0 + residual + pool1 fused:
// agg = dis[i]^2*h[i] + sum_e dis[s]*dis[i]*ea[e]*h[s];  hv = agg + x[i]
// px[c0[i]] max= lrelu(hv);  ox[c0[i]] max= x[i]
__global__ __launch_bounds__(256) void gather0(
        const __hip_bfloat16* __restrict__ h16, const float* __restrict__ x,
        const int* __restrict__ ei0, const float* __restrict__ ea,
        const float* __restrict__ dis, const int* __restrict__ offs,
        const int* __restrict__ cnt, const int* __restrict__ csr,
        const int* __restrict__ c0,
        float* __restrict__ px, float* __restrict__ ox)
{
    const int wid = (blockIdx.x * 256 + threadIdx.x) >> 6;
    if (wid >= N_NODES) return;
    const int lane = threadIdx.x & 63;
    const float di = dis[wid];
    const unsigned int* hrows = (const unsigned int*)h16;

    float2 hs = ld_bf16x2(hrows + (size_t)wid * 64, lane);
    float a0 = di * di * hs.x, a1 = di * di * hs.y;
    float b0 = 0.f, b1 = 0.f;

    const int base = offs[wid], n = cnt[wid];
    int k = 0;
    for (; k + 1 < n; k += 2) {
        int e1 = csr[base + k], e2 = csr[base + k + 1];
        int s1 = ei0[e1], s2 = ei0[e2];
        float w1 = dis[s1] * di * ea[e1];
        float w2 = dis[s2] * di * ea[e2];
        float2 h1 = ld_bf16x2(hrows + (size_t)s1 * 64, lane);
        float2 h2v = ld_bf16x2(hrows + (size_t)s2 * 64, lane);
        a0 += w1 * h1.x; a1 += w1 * h1.y;
        b0 += w2 * h2v.x; b1 += w2 * h2v.y;
    }
    if (k < n) {
        int e1 = csr[base + k];
        int s1 = ei0[e1];
        float w1 = dis[s1] * di * ea[e1];
        float2 h1 = ld_bf16x2(hrows + (size_t)s1 * 64, lane);
        a0 += w1 * h1.x; a1 += w1 * h1.y;
    }
    a0 += b0; a1 += b1;

    float2 xv = *(const float2*)&x[(size_t)wid * DIM + lane * 2];
    const int c = c0[wid];
    float* pp = &px[(size_t)c * DIM + lane * 2];
    atomicMaxF(pp + 0, lrelu(a0 + xv.x));
    atomicMaxF(pp + 1, lrelu(a1 + xv.y));
    float* op = &ox[(size_t)c * DIM + lane * 2];
    atomicMaxF(op + 0, xv.x);
    atomicMaxF(op + 1, xv.y);
}

// mpnn2 + lrelu + global max pool fused:
// agg2 = dis2[i]^2*hm2[i] + sum_e dis2[s]*dis2[i]*ea[e]*hm2[s]
// gmax[pb2[i]] max= lrelu(agg2)
__global__ __launch_bounds__(256) void gather2(
        const float* __restrict__ hm2,
        const int* __restrict__ src2, const float* __restrict__ ea,
        const float* __restrict__ dis, const int* __restrict__ offs,
        const int* __restrict__ cnt, const int* __restrict__ csr,
        const int* __restrict__ pb2, float* __restrict__ gmax)
{
    const int wid = (blockIdx.x * 256 + threadIdx.x) >> 6;
    if (wid >= NPOOL1) return;
    const int lane = threadIdx.x & 63;
    const float di = dis[wid];

    float2 hs = *(const float2*)&hm2[(size_t)wid * DIM + lane * 2];
    float a0 = di * di * hs.x, a1 = di * di * hs.y;
    float b0 = 0.f, b1 = 0.f;

    const int base = offs[wid], n = cnt[wid];
    int k = 0;
    for (; k + 1 < n; k += 2) {
        int e1 = csr[base + k], e2 = csr[base + k + 1];
        int s1 = src2[e1], s2 = src2[e2];
        float w1 = dis[s1] * di * ea[e1];
        float w2 = dis[s2] * di * ea[e2];
        float2 h1 = *(const float2*)&hm2[(size_t)s1 * DIM + lane * 2];
        float2 h2v = *(const float2*)&hm2[(size_t)s2 * DIM + lane * 2];
        a0 += w1 * h1.x; a1 += w1 * h1.y;
        b0 += w2 * h2v.x; b1 += w2 * h2v.y;
    }
    if (k < n) {
        int e1 = csr[base + k];
        int s1 = src2[e1];
        float w1 = dis[s1] * di * ea[e1];
        float2 h1 = *(const float2*)&hm2[(size_t)s1 * DIM + lane * 2];
        a0 += w1 * h1.x; a1 += w1 * h1.y;
    }
    a0 += b0; a1 += b1;

    const int g = pb2[wid];
    float* gp = &gmax[(size_t)g * DIM + lane * 2];
    atomicMaxF(gp + 0, lrelu(a0));
    atomicMaxF(gp + 1, lrelu(a1));
}

// ---------------- pooling helpers ----------------
// px <- fix(px) + fix(ox)   (h2 in place)
__global__ __launch_bounds__(256) void h2k_inplace(float* __restrict__ px, const float* __restrict__ ox, int total) {
    int idx = blockIdx.x * 256 + threadIdx.x;
    if (idx < total) {
        float a = px[idx], b = ox[idx];
        a = (a == -INFINITY) ? 0.f : a;
        b = (b == -INFINITY) ? 0.f : b;
        px[idx] = a + b;
    }
}
__global__ __launch_bounds__(256) void pool2(const float* __restrict__ h2, const int* __restrict__ c1,
                                             float* __restrict__ x2, int total) {
    int idx = blockIdx.x * 256 + threadIdx.x;
    if (idx < total) {
        int i = idx >> 7, d = idx & 127;
        atomicMaxF(&x2[(size_t)c1[i] * DIM + d], lrelu(h2[idx]));
    }
}
__global__ __launch_bounds__(256) void fixinf(float* __restrict__ p, int total) {
    int idx = blockIdx.x * 256 + threadIdx.x;
    if (idx < total && p[idx] == -INFINITY) p[idx] = 0.f;
}
__global__ __launch_bounds__(256) void segmax_i32(const int* __restrict__ map, const int* __restrict__ vals,
                                                  int* __restrict__ out, int n) {
    int i = blockIdx.x * 256 + threadIdx.x;
    if (i < n) atomicMax(&out[map[i]], vals[i]);
}

// ---------------- head ----------------
__global__ __launch_bounds__(128) void head(
        const float* __restrict__ gmax, const float* __restrict__ energy,
        const float* __restrict__ emb_w, const float* __restrict__ emb_b,
        const float* __restrict__ emb_g, const float* __restrict__ emb_be,
        const float* __restrict__ lw1, const float* __restrict__ lb1,
        const float* __restrict__ lg, const float* __restrict__ lbe,
        const float* __restrict__ lw2, const float* __restrict__ lb2,
        float* __restrict__ out)
{
    const int g = blockIdx.x;
    const int t = threadIdx.x;
    __shared__ float z[136];
    __shared__ float red[128];

    {
        float v = gmax[(size_t)g * DIM + t];
        z[t] = (v == -INFINITY) ? 0.f : v;
    }
    if (t < 8) {
        float s = 0.f;
        #pragma unroll
        for (int k = 0; k < 21; ++k) s += energy[g * 21 + k] * emb_w[t * 21 + k];
        s = (s + emb_b[t]) * emb_g[t] + emb_be[t];
        z[128 + t] = lrelu(s);
    }
    __syncthreads();
    float s = 0.f;
    #pragma unroll 8
    for (int k = 0; k < 136; ++k) s += z[k] * lw1[t * 136 + k];
    float z2 = lrelu((s + lb1[t]) * lg[t] + lbe[t]);
    red[t] = z2 * lw2[t];
    __syncthreads();
    if (t == 0) {
        float acc = lb2[0];
        for (int k = 0; k < 128; ++k) acc += red[k];
        out[g] = acc;
    }
}

extern "C" void kernel_launch(void* const* d_in, const int* in_sizes, int n_in,
                              void* d_out, int out_size, void* d_ws, size_t ws_size,
                              hipStream_t stream) {
    const float* x        = (const float*)d_in[0];
    const float* edge_attr= (const float*)d_in[1];
    const float* energy   = (const float*)d_in[2];
    const float* w0a = (const float*)d_in[3];
    const float* b0a = (const float*)d_in[4];
    const float* g0  = (const float*)d_in[5];
    const float* be0 = (const float*)d_in[6];
    const float* w0b = (const float*)d_in[7];
    const float* b0b = (const float*)d_in[8];
    const float* w2a = (const float*)d_in[15];
    const float* b2a = (const float*)d_in[16];
    const float* g2  = (const float*)d_in[17];
    const float* be2 = (const float*)d_in[18];
    const float* w2b = (const float*)d_in[19];
    const float* b2b = (const float*)d_in[20];
    const float* emb_w  = (const float*)d_in[21];
    const float* emb_b  = (const float*)d_in[22];
    const float* emb_g  = (const float*)d_in[23];
    const float* emb_be = (const float*)d_in[24];
    const float* lw1 = (const float*)d_in[25];
    const float* lb1 = (const float*)d_in[26];
    const float* lg  = (const float*)d_in[27];
    const float* lbe = (const float*)d_in[28];
    const float* lw2 = (const float*)d_in[29];
    const float* lb2 = (const float*)d_in[30];
    const int* ei0   = (const int*)d_in[31];
    const int* ei1   = ei0 + N_EDGES;
    const int* batch = (const int*)d_in[32];
    const int* c0    = (const int*)d_in[33];
    const int* c1    = (const int*)d_in[34];
    float* out = (float*)d_out;

    // ---- workspace layout (peak ~85.2 MB; < 103.3 MB proven in round 1) ----
    char* ws = (char*)d_ws;
    __hip_bfloat16* h16 = (__hip_bfloat16*)(ws + 0);  // [N,128] bf16, live mlp0..gather0
    float* px    = (float*)(ws + 25600000);           // [N0,128]  (h2 in place later)
    float* ox    = (float*)(ws + 51200000);           // [N0,128]
    int*   csr0  = (int*)(ws + 76800000);             // [E]
    float* deg0  = (float*)(ws + 83200000);           // [N]  -> dis0
    int*   cnt0  = (int*)(ws + 83600000);             // [N]
    int*   offs0 = (int*)(ws + 84000000);             // [N]
    int*   fill0 = (int*)(ws + 84400000);             // [N]
    int*   bsum  = (int*)(ws + 84800000);             // [<=512] (reused)
    int*   pb    = (int*)(ws + 84804096);             // [N0]
    int*   pb2   = (int*)(ws + 85004096);             // [N1]
    float* gmax  = (float*)(ws + 85104096);           // [64,128]
    // phase-3 aliases (h16 region dead after gather0; ox dead after h2k)
    int*   src2  = (int*)(ws + 0);                    // [E]
    int*   dst2  = (int*)(ws + 6400000);              // [E]
    int*   csr2  = (int*)(ws + 12800000);             // [E]
    float* deg2  = (float*)(ws + 19200000);           // [N1] -> dis2
    int*   cnt2  = (int*)(ws + 19300000);             // [N1]
    int*   offs2 = (int*)(ws + 19400000);             // [N1]
    int*   fill2 = (int*)(ws + 19500000);             // [N1]
    float* x2    = (float*)(ws + 51200000);           // [N1,128] (alias ox)
    float* hm2   = (float*)(ws + 64000000);           // [N1,128]

    (void)in_sizes; (void)n_in; (void)out_size; (void)ws_size;

    const int NB0 = (N_NODES + 255) / 256;   // 391
    const int NB1 = (NPOOL1 + 255) / 256;    // 98

    // ---- mpnn0: MLP + CSR build + gather (fused residual+pool1) ----
    fill_f32<<<NB0, 256, 0, stream>>>(deg0, N_NODES, 1.0f);
    fill_i32<<<NB0, 256, 0, stream>>>(cnt0, N_NODES, 0);
    mlp_fused<128, 128, __hip_bfloat16><<<(N_NODES + 15) / 16, 256, 0, stream>>>(
        x, N_NODES, w0a, b0a, g0, be0, w0b, b0b, h16);
    count0<<<(N_EDGES + 255) / 256, 256, 0, stream>>>(ei0, ei1, deg0, cnt0, N_EDGES);
    rsqrt_ip<<<NB0, 256, 0, stream>>>(deg0, N_NODES);
    scan_blk<<<NB0, 256, 0, stream>>>(cnt0, offs0, bsum, N_NODES);
    scan_top<<<1, 512, 0, stream>>>(bsum, NB0);
    scan_add<<<NB0, 256, 0, stream>>>(offs0, bsum, fill0, N_NODES);
    place<<<(N_EDGES + 255) / 256, 256, 0, stream>>>(ei1, fill0, csr0, N_EDGES);

    fill_f32<<<(NPOOL0 * DIM + 255) / 256, 256, 0, stream>>>(px, NPOOL0 * DIM, -INFINITY);
    fill_f32<<<(NPOOL0 * DIM + 255) / 256, 256, 0, stream>>>(ox, NPOOL0 * DIM, -INFINITY);
    gather0<<<(N_NODES * 64) / 256, 256, 0, stream>>>(h16, x, ei0, edge_attr, deg0,
                                                      offs0, cnt0, csr0, c0, px, ox);

    // ---- pool bookkeeping ----
    fill_i32<<<(NPOOL0 + 255) / 256, 256, 0, stream>>>(pb, NPOOL0, 0);
    segmax_i32<<<NB0, 256, 0, stream>>>(c0, batch, pb, N_NODES);
    h2k_inplace<<<(NPOOL0 * DIM + 255) / 256, 256, 0, stream>>>(px, ox, NPOOL0 * DIM);

    fill_f32<<<(NPOOL1 * DIM + 255) / 256, 256, 0, stream>>>(x2, NPOOL1 * DIM, -INFINITY);
    pool2<<<(NPOOL0 * DIM + 255) / 256, 256, 0, stream>>>(px, c1, x2, NPOOL0 * DIM);
    fixinf<<<(NPOOL1 * DIM + 255) / 256, 256, 0, stream>>>(x2, NPOOL1 * DIM);
    fill_i32<<<NB1, 256, 0, stream>>>(pb2, NPOOL1, 0);
    segmax_i32<<<(NPOOL0 + 255) / 256, 256, 0, stream>>>(c1, pb, pb2, NPOOL0);

    // ---- mpnn2: edge remap + MLP + CSR build + gather (fused lrelu+gpool) ----
    fill_f32<<<NB1, 256, 0, stream>>>(deg2, NPOOL1, 1.0f);
    fill_i32<<<NB1, 256, 0, stream>>>(cnt2, NPOOL1, 0);
    edgemap<<<(N_EDGES + 255) / 256, 256, 0, stream>>>(ei0, ei1, c0, c1, src2, dst2, deg2, cnt2, N_EDGES);
    rsqrt_ip<<<NB1, 256, 0, stream>>>(deg2, NPOOL1);
    mlp_fused<128, 256, float><<<(NPOOL1 + 15) / 16, 256, 0, stream>>>(
        x2, NPOOL1, w2a, b2a, g2, be2, w2b, b2b, hm2);
    scan_blk<<<NB1, 256, 0, stream>>>(cnt2, offs2, bsum, NPOOL1);
    scan_top<<<1, 512, 0, stream>>>(bsum, NB1);
    scan_add<<<NB1, 256, 0, stream>>>(offs2, bsum, fill2, NPOOL1);
    place<<<(N_EDGES + 255) / 256, 256, 0, stream>>>(dst2, fill2, csr2, N_EDGES);

    fill_f32<<<(NGRAPH * DIM + 255) / 256, 256, 0, stream>>>(gmax, NGRAPH * DIM, -INFINITY);
    gather2<<<(NPOOL1 * 64) / 256, 256, 0, stream>>>(hm2, src2, edge_attr, deg2,
                                                     offs2, cnt2, csr2, pb2, gmax);

    // ---- head ----
    head<<<NGRAPH, 128, 0, stream>>>(gmax, energy, emb_w, emb_b, emb_g, emb_be,
                                     lw1, lb1, lg, lbe, lw2, lb2, out);
}

// Round 4
// 1888.132 us; speedup vs baseline: 3.5707x; 1.1600x over previous
//
#include <hip/hip_runtime.h>
#include <hip/hip_bf16.h>
#include <math.h>

#define N_NODES 100000
#define N_EDGES 1600000
#define DIM     128
#define NPOOL0  50000
#define NPOOL1  25000
#define NGRAPH  64

__device__ __forceinline__ float lrelu(float v) { return v > 0.f ? v : 0.01f * v; }

// float atomic max: signed-max for v>=0, unsigned-min for v<0 (monotone, -inf init; verified r1/r2)
__device__ __forceinline__ void atomicMaxF(float* addr, float val) {
    if (val >= 0.f) atomicMax((int*)addr, __float_as_int(val));
    else            atomicMin((unsigned int*)addr, __float_as_uint(val));
}

// ---------------- fills ----------------
__global__ __launch_bounds__(256) void fill_f32(float* __restrict__ p, int n, float v) {
    int i = blockIdx.x * 256 + threadIdx.x;
    if (i < n) p[i] = v;
}
__global__ __launch_bounds__(256) void fill_i32(int* __restrict__ p, int n, int v) {
    int i = blockIdx.x * 256 + threadIdx.x;
    if (i < n) p[i] = v;
}

// ---------------- fused 2-layer MLP: Y = lrelu((X@W1^T+b1)*g+be) @ W2^T + b2 ----------------
template<int KIN, int HID, typename OT>
__global__ __launch_bounds__(256) void mlp_fused(
        const float* __restrict__ X, int R,
        const float* __restrict__ W1, const float* __restrict__ B1,
        const float* __restrict__ G1, const float* __restrict__ BE1,
        const float* __restrict__ W2, const float* __restrict__ B2,
        OT* __restrict__ Y)
{
    constexpr int TR = 16;
    constexpr int WSC = (HID > 128) ? HID : 128;
    __shared__ float xs[TR][KIN + 4];
    __shared__ float ts[TR][HID + 4];
    __shared__ float ws[32 * WSC];

    const int tid = threadIdx.x;
    const int ty = tid >> 4;
    const int tx = tid & 15;
    const int r0 = blockIdx.x * TR;

    {
        const int r = r0 + ty;
        const int cb = tx * (KIN / 16);
        if (r < R) {
            #pragma unroll
            for (int q = 0; q < KIN / 16; q += 4)
                *(float4*)&xs[ty][cb + q] = *(const float4*)&X[(size_t)r * KIN + cb + q];
        } else {
            #pragma unroll
            for (int q = 0; q < KIN / 16; q += 4)
                *(float4*)&xs[ty][cb + q] = float4{0.f, 0.f, 0.f, 0.f};
        }
    }

    constexpr int NJ1 = HID / 16;
    float acc[NJ1];
    #pragma unroll
    for (int j = 0; j < NJ1; ++j) acc[j] = 0.f;

    for (int kc = 0; kc < KIN; kc += 32) {
        __syncthreads();
        for (int lin = tid; lin < HID * 8; lin += 256) {
            const int c = lin >> 3, q = lin & 7;
            float4 v = *(const float4*)&W1[(size_t)c * KIN + kc + q * 4];
            ws[(q * 4 + 0) * HID + c] = v.x;
            ws[(q * 4 + 1) * HID + c] = v.y;
            ws[(q * 4 + 2) * HID + c] = v.z;
            ws[(q * 4 + 3) * HID + c] = v.w;
        }
        __syncthreads();
        #pragma unroll
        for (int kk = 0; kk < 32; ++kk) {
            const float xv = xs[ty][kc + kk];
            #pragma unroll
            for (int j = 0; j < NJ1; ++j) acc[j] += xv * ws[kk * HID + tx + 16 * j];
        }
    }
    __syncthreads();
    #pragma unroll
    for (int j = 0; j < NJ1; ++j) {
        const int c = tx + 16 * j;
        const float v = (acc[j] + B1[c]) * G1[c] + BE1[c];
        ts[ty][c] = lrelu(v);
    }

    float acc2[8];
    #pragma unroll
    for (int j = 0; j < 8; ++j) acc2[j] = 0.f;

    for (int kc = 0; kc < HID; kc += 32) {
        __syncthreads();
        for (int lin = tid; lin < 128 * 8; lin += 256) {
            const int c = lin >> 3, q = lin & 7;
            float4 v = *(const float4*)&W2[(size_t)c * HID + kc + q * 4];
            ws[(q * 4 + 0) * 128 + c] = v.x;
            ws[(q * 4 + 1) * 128 + c] = v.y;
            ws[(q * 4 + 2) * 128 + c] = v.z;
            ws[(q * 4 + 3) * 128 + c] = v.w;
        }
        __syncthreads();
        #pragma unroll
        for (int kk = 0; kk < 32; ++kk) {
            const float tv = ts[ty][kc + kk];
            #pragma unroll
            for (int j = 0; j < 8; ++j) acc2[j] += tv * ws[kk * 128 + tx + 16 * j];
        }
    }
    const int r = r0 + ty;
    if (r < R) {
        #pragma unroll
        for (int j = 0; j < 8; ++j) {
            const int c = tx + 16 * j;
            const float v = acc2[j] + B2[c];
            if constexpr (sizeof(OT) == 2) Y[(size_t)r * 128 + c] = __float2bfloat16(v);
            else                           Y[(size_t)r * 128 + c] = v;
        }
    }
}

// ---------------- CSR build ----------------
__global__ __launch_bounds__(256) void count0(const int* __restrict__ src, const int* __restrict__ dst,
                                              float* __restrict__ deg, int* __restrict__ cnt, int E) {
    int e = blockIdx.x * 256 + threadIdx.x;
    if (e < E) {
        atomicAdd(&deg[src[e]], 1.0f);
        atomicAdd(&cnt[dst[e]], 1);
    }
}
__global__ __launch_bounds__(256) void rsqrt_ip(float* __restrict__ p, int n) {
    int i = blockIdx.x * 256 + threadIdx.x;
    if (i < n) p[i] = rsqrtf(p[i]);
}
__global__ __launch_bounds__(256) void scan_blk(const int* __restrict__ cnt, int* __restrict__ offs,
                                                int* __restrict__ bsum, int n) {
    __shared__ int s[256];
    const int tid = threadIdx.x;
    const int i = blockIdx.x * 256 + tid;
    int v = (i < n) ? cnt[i] : 0;
    s[tid] = v;
    __syncthreads();
    #pragma unroll
    for (int d = 1; d < 256; d <<= 1) {
        int t = (tid >= d) ? s[tid - d] : 0;
        __syncthreads();
        s[tid] += t;
        __syncthreads();
    }
    if (i < n) offs[i] = s[tid] - v;
    if (tid == 255) bsum[blockIdx.x] = s[255];
}
__global__ __launch_bounds__(512) void scan_top(int* __restrict__ bsum, int nb) {
    __shared__ int s[512];
    const int tid = threadIdx.x;
    int v = (tid < nb) ? bsum[tid] : 0;
    s[tid] = v;
    __syncthreads();
    #pragma unroll
    for (int d = 1; d < 512; d <<= 1) {
        int t = (tid >= d) ? s[tid - d] : 0;
        __syncthreads();
        s[tid] += t;
        __syncthreads();
    }
    if (tid < nb) bsum[tid] = s[tid] - v;
}
__global__ __launch_bounds__(256) void scan_add(int* __restrict__ offs, const int* __restrict__ bsum,
                                                int* __restrict__ fill, int n) {
    int i = blockIdx.x * 256 + threadIdx.x;
    if (i < n) {
        int o = offs[i] + bsum[i >> 8];
        offs[i] = o;
        fill[i] = o;
    }
}
// counting-sort placement WITH payload packing: pack[pos] = {src, dis[src]*ea[e]}
__global__ __launch_bounds__(256) void place_pack(const int* __restrict__ dst, const int* __restrict__ srcA,
                                                  const float* __restrict__ ea, const float* __restrict__ dis,
                                                  int* __restrict__ fill, int2* __restrict__ pack, int E) {
    int e = blockIdx.x * 256 + threadIdx.x;
    if (e < E) {
        int d = dst[e];
        int s = srcA[e];
        int pos = atomicAdd(&fill[d], 1);
        pack[pos] = make_int2(s, __float_as_int(dis[s] * ea[e]));
    }
}
__global__ __launch_bounds__(256) void edgemap(
        const int* __restrict__ ei0, const int* __restrict__ ei1,
        const int* __restrict__ c0, const int* __restrict__ c1,
        int* __restrict__ src2, int* __restrict__ dst2,
        float* __restrict__ deg2, int* __restrict__ cnt2, int E)
{
    int e = blockIdx.x * 256 + threadIdx.x;
    if (e < E) {
        int s = c1[c0[ei0[e]]];
        int d = c1[c0[ei1[e]]];
        src2[e] = s;
        dst2[e] = d;
        atomicAdd(&deg2[s], 1.0f);
        atomicAdd(&cnt2[d], 1);
    }
}

// ---------------- gather-reduce (one wave per dst node; packed CSR; readlane broadcast) ----------------
// per edge: s,w broadcast from coalesced pack chunk via v_readlane -> single dependent row load
#define EDGE_ITER(K, A0, A1) {                                                  \
    int s_ = __builtin_amdgcn_readlane(pv.x, (K));                              \
    float w_ = __int_as_float(__builtin_amdgcn_readlane(pv.y, (K)));            \
    unsigned hv_ = hrows[(size_t)s_ * 64 + lane];                               \
    float c_ = w_ * di;                                                         \
    A0 += c_ * __uint_as_float(hv_ << 16);                                      \
    A1 += c_ * __uint_as_float(hv_ & 0xFFFF0000u); }

// mpnn0 + residual + pool1 fused
__global__ __launch_bounds__(256) void gather0(
        const __hip_bfloat16* __restrict__ h16, const float* __restrict__ x,
        const float* __restrict__ dis, const int* __restrict__ offs,
        const int* __restrict__ cnt, const int2* __restrict__ pack,
        const int* __restrict__ c0,
        float* __restrict__ px, float* __restrict__ ox)
{
    const int wid = (blockIdx.x * 256 + threadIdx.x) >> 6;
    if (wid >= N_NODES) return;
    const int lane = threadIdx.x & 63;
    const float di = dis[wid];
    const unsigned* hrows = (const unsigned*)h16;

    unsigned hself = hrows[(size_t)wid * 64 + lane];
    float a0 = di * di * __uint_as_float(hself << 16);
    float a1 = di * di * __uint_as_float(hself & 0xFFFF0000u);
    float b0 = 0.f, b1 = 0.f;

    const int base = offs[wid], n = cnt[wid];
    int k0 = 0;
    for (; k0 + 64 <= n; k0 += 64) {
        int2 pv = pack[base + k0 + lane];
        #pragma unroll
        for (int k = 0; k < 64; k += 2) {
            EDGE_ITER(k,     a0, a1);
            EDGE_ITER(k + 1, b0, b1);
        }
    }
    const int rem = n - k0;
    if (rem > 0) {
        int2 pv = (lane < rem) ? pack[base + k0 + lane] : make_int2(0, 0);
        #pragma unroll 4
        for (int k = 0; k < rem; ++k) EDGE_ITER(k, a0, a1);
    }
    a0 += b0; a1 += b1;

    float2 xv = *(const float2*)&x[(size_t)wid * DIM + lane * 2];
    const int c = c0[wid];
    float* pp = &px[(size_t)c * DIM + lane * 2];
    atomicMaxF(pp + 0, lrelu(a0 + xv.x));
    atomicMaxF(pp + 1, lrelu(a1 + xv.y));
    float* op = &ox[(size_t)c * DIM + lane * 2];
    atomicMaxF(op + 0, xv.x);
    atomicMaxF(op + 1, xv.y);
}

// mpnn2 + lrelu + global max pool fused (hm2 in bf16)
__global__ __launch_bounds__(256) void gather2(
        const __hip_bfloat16* __restrict__ hm2,
        const float* __restrict__ dis, const int* __restrict__ offs,
        const int* __restrict__ cnt, const int2* __restrict__ pack,
        const int* __restrict__ pb2, float* __restrict__ gmax)
{
    const int wid = (blockIdx.x * 256 + threadIdx.x) >> 6;
    if (wid >= NPOOL1) return;
    const int lane = threadIdx.x & 63;
    const float di = dis[wid];
    const unsigned* hrows = (const unsigned*)hm2;

    unsigned hself = hrows[(size_t)wid * 64 + lane];
    float a0 = di * di * __uint_as_float(hself << 16);
    float a1 = di * di * __uint_as_float(hself & 0xFFFF0000u);
    float b0 = 0.f, b1 = 0.f;

    const int base = offs[wid], n = cnt[wid];
    int k0 = 0;
    for (; k0 + 64 <= n; k0 += 64) {
        int2 pv = pack[base + k0 + lane];
        #pragma unroll
        for (int k = 0; k < 64; k += 2) {
            EDGE_ITER(k,     a0, a1);
            EDGE_ITER(k + 1, b0, b1);
        }
    }
    const int rem = n - k0;
    if (rem > 0) {
        int2 pv = (lane < rem) ? pack[base + k0 + lane] : make_int2(0, 0);
        #pragma unroll 4
        for (int k = 0; k < rem; ++k) EDGE_ITER(k, a0, a1);
    }
    a0 += b0; a1 += b1;

    const int g = pb2[wid];
    float* gp = &gmax[(size_t)g * DIM + lane * 2];
    atomicMaxF(gp + 0, lrelu(a0));
    atomicMaxF(gp + 1, lrelu(a1));
}

// ---------------- pooling helpers ----------------
// fused h2k + pool2: x2[c1[i]] max= lrelu(fix(px)+fix(ox))
__global__ __launch_bounds__(256) void pool2_fused(const float* __restrict__ px, const float* __restrict__ ox,
                                                   const int* __restrict__ c1, float* __restrict__ x2, int total) {
    int idx = blockIdx.x * 256 + threadIdx.x;
    if (idx < total) {
        int i = idx >> 7, d = idx & 127;
        float a = px[idx], b = ox[idx];
        a = (a == -INFINITY) ? 0.f : a;
        b = (b == -INFINITY) ? 0.f : b;
        atomicMaxF(&x2[(size_t)c1[i] * DIM + d], lrelu(a + b));
    }
}
__global__ __launch_bounds__(256) void fixinf(float* __restrict__ p, int total) {
    int idx = blockIdx.x * 256 + threadIdx.x;
    if (idx < total && p[idx] == -INFINITY) p[idx] = 0.f;
}
__global__ __launch_bounds__(256) void segmax_i32(const int* __restrict__ map, const int* __restrict__ vals,
                                                  int* __restrict__ out, int n) {
    int i = blockIdx.x * 256 + threadIdx.x;
    if (i < n) atomicMax(&out[map[i]], vals[i]);
}

// ---------------- head ----------------
__global__ __launch_bounds__(128) void head(
        const float* __restrict__ gmax, const float* __restrict__ energy,
        const float* __restrict__ emb_w, const float* __restrict__ emb_b,
        const float* __restrict__ emb_g, const float* __restrict__ emb_be,
        const float* __restrict__ lw1, const float* __restrict__ lb1,
        const float* __restrict__ lg, const float* __restrict__ lbe,
        const float* __restrict__ lw2, const float* __restrict__ lb2,
        float* __restrict__ out)
{
    const int g = blockIdx.x;
    const int t = threadIdx.x;
    __shared__ float z[136];
    __shared__ float red[128];

    {
        float v = gmax[(size_t)g * DIM + t];
        z[t] = (v == -INFINITY) ? 0.f : v;
    }
    if (t < 8) {
        float s = 0.f;
        #pragma unroll
        for (int k = 0; k < 21; ++k) s += energy[g * 21 + k] * emb_w[t * 21 + k];
        s = (s + emb_b[t]) * emb_g[t] + emb_be[t];
        z[128 + t] = lrelu(s);
    }
    __syncthreads();
    float s = 0.f;
    #pragma unroll 8
    for (int k = 0; k < 136; ++k) s += z[k] * lw1[t * 136 + k];
    float z2 = lrelu((s + lb1[t]) * lg[t] + lbe[t]);
    red[t] = z2 * lw2[t];
    __syncthreads();
    if (t == 0) {
        float acc = lb2[0];
        for (int k = 0; k < 128; ++k) acc += red[k];
        out[g] = acc;
    }
}

extern "C" void kernel_launch(void* const* d_in, const int* in_sizes, int n_in,
                              void* d_out, int out_size, void* d_ws, size_t ws_size,
                              hipStream_t stream) {
    const float* x        = (const float*)d_in[0];
    const float* edge_attr= (const float*)d_in[1];
    const float* energy   = (const float*)d_in[2];
    const float* w0a = (const float*)d_in[3];
    const float* b0a = (const float*)d_in[4];
    const float* g0  = (const float*)d_in[5];
    const float* be0 = (const float*)d_in[6];
    const float* w0b = (const float*)d_in[7];
    const float* b0b = (const float*)d_in[8];
    const float* w2a = (const float*)d_in[15];
    const float* b2a = (const float*)d_in[16];
    const float* g2  = (const float*)d_in[17];
    const float* be2 = (const float*)d_in[18];
    const float* w2b = (const float*)d_in[19];
    const float* b2b = (const float*)d_in[20];
    const float* emb_w  = (const float*)d_in[21];
    const float* emb_b  = (const float*)d_in[22];
    const float* emb_g  = (const float*)d_in[23];
    const float* emb_be = (const float*)d_in[24];
    const float* lw1 = (const float*)d_in[25];
    const float* lb1 = (const float*)d_in[26];
    const float* lg  = (const float*)d_in[27];
    const float* lbe = (const float*)d_in[28];
    const float* lw2 = (const float*)d_in[29];
    const float* lb2 = (const float*)d_in[30];
    const int* ei0   = (const int*)d_in[31];
    const int* ei1   = ei0 + N_EDGES;
    const int* batch = (const int*)d_in[32];
    const int* c0    = (const int*)d_in[33];
    const int* c1    = (const int*)d_in[34];
    float* out = (float*)d_out;

    // ---- workspace layout (peak ~92 MB) ----
    char* ws = (char*)d_ws;
    // phase 1 (mpnn0): region A = h16 [N,128] bf16 (0..25.6M)
    __hip_bfloat16* h16 = (__hip_bfloat16*)(ws + 0);
    float* px    = (float*)(ws + 25600000);           // [N0,128] f32 (25.6..51.2)
    float* ox    = (float*)(ws + 51200000);           // [N0,128] f32 (51.2..76.8)
    int2*  pack0 = (int2*)(ws + 76800000);            // [E] int2  (76.8..89.6)
    float* deg0  = (float*)(ws + 89600000);           // [N] -> dis0
    int*   cnt0  = (int*)(ws + 90000000);
    int*   offs0 = (int*)(ws + 90400000);
    int*   fill0 = (int*)(ws + 90800000);
    int*   bsum  = (int*)(ws + 91200000);             // [<=512]
    int*   pb    = (int*)(ws + 91204096);             // [N0]
    int*   pb2   = (int*)(ws + 91404096);             // [N1]
    float* gmax  = (float*)(ws + 91504096);           // [64,128]
    float* deg2  = (float*)(ws + 91540864);           // [N1] -> dis2
    int*   cnt2  = (int*)(ws + 91640864);
    int*   offs2 = (int*)(ws + 91740864);
    int*   fill2 = (int*)(ws + 91840864);
    // phase 2/3 aliases: h16 dead after gather0; px/ox dead after pool2_fused; pack0 dead after gather0
    float* x2    = (float*)(ws + 0);                  // [N1,128] f32 (0..12.8)
    __hip_bfloat16* hm2 = (__hip_bfloat16*)(ws + 12800000);  // [N1,128] bf16 (12.8..19.2)
    int*   src2  = (int*)(ws + 25600000);             // [E] (px region)
    int*   dst2  = (int*)(ws + 32000000);             // [E]
    int2*  pack2 = (int2*)(ws + 76800000);            // [E] int2 (pack0 region)

    (void)in_sizes; (void)n_in; (void)out_size; (void)ws_size;

    const int NB0 = (N_NODES + 255) / 256;   // 391
    const int NB1 = (NPOOL1 + 255) / 256;    // 98

    // ---- mpnn0: MLP + CSR(pack) build + gather (fused residual+pool1) ----
    fill_f32<<<NB0, 256, 0, stream>>>(deg0, N_NODES, 1.0f);
    fill_i32<<<NB0, 256, 0, stream>>>(cnt0, N_NODES, 0);
    mlp_fused<128, 128, __hip_bfloat16><<<(N_NODES + 15) / 16, 256, 0, stream>>>(
        x, N_NODES, w0a, b0a, g0, be0, w0b, b0b, h16);
    count0<<<(N_EDGES + 255) / 256, 256, 0, stream>>>(ei0, ei1, deg0, cnt0, N_EDGES);
    rsqrt_ip<<<NB0, 256, 0, stream>>>(deg0, N_NODES);
    scan_blk<<<NB0, 256, 0, stream>>>(cnt0, offs0, bsum, N_NODES);
    scan_top<<<1, 512, 0, stream>>>(bsum, NB0);
    scan_add<<<NB0, 256, 0, stream>>>(offs0, bsum, fill0, N_NODES);
    place_pack<<<(N_EDGES + 255) / 256, 256, 0, stream>>>(ei1, ei0, edge_attr, deg0, fill0, pack0, N_EDGES);

    fill_f32<<<(NPOOL0 * DIM + 255) / 256, 256, 0, stream>>>(px, NPOOL0 * DIM, -INFINITY);
    fill_f32<<<(NPOOL0 * DIM + 255) / 256, 256, 0, stream>>>(ox, NPOOL0 * DIM, -INFINITY);
    gather0<<<(N_NODES * 64) / 256, 256, 0, stream>>>(h16, x, deg0, offs0, cnt0, pack0, c0, px, ox);

    // ---- pool bookkeeping + pool2 ----
    fill_i32<<<(NPOOL0 + 255) / 256, 256, 0, stream>>>(pb, NPOOL0, 0);
    segmax_i32<<<NB0, 256, 0, stream>>>(c0, batch, pb, N_NODES);
    fill_f32<<<(NPOOL1 * DIM + 255) / 256, 256, 0, stream>>>(x2, NPOOL1 * DIM, -INFINITY);
    pool2_fused<<<(NPOOL0 * DIM + 255) / 256, 256, 0, stream>>>(px, ox, c1, x2, NPOOL0 * DIM);
    fixinf<<<(NPOOL1 * DIM + 255) / 256, 256, 0, stream>>>(x2, NPOOL1 * DIM);
    fill_i32<<<NB1, 256, 0, stream>>>(pb2, NPOOL1, 0);
    segmax_i32<<<(NPOOL0 + 255) / 256, 256, 0, stream>>>(c1, pb, pb2, NPOOL0);

    // ---- mpnn2: edge remap + MLP + CSR(pack) build + gather (fused lrelu+gpool) ----
    fill_f32<<<NB1, 256, 0, stream>>>(deg2, NPOOL1, 1.0f);
    fill_i32<<<NB1, 256, 0, stream>>>(cnt2, NPOOL1, 0);
    edgemap<<<(N_EDGES + 255) / 256, 256, 0, stream>>>(ei0, ei1, c0, c1, src2, dst2, deg2, cnt2, N_EDGES);
    rsqrt_ip<<<NB1, 256, 0, stream>>>(deg2, NPOOL1);
    scan_blk<<<NB1, 256, 0, stream>>>(cnt2, offs2, bsum, NPOOL1);
    scan_top<<<1, 512, 0, stream>>>(bsum, NB1);
    scan_add<<<NB1, 256, 0, stream>>>(offs2, bsum, fill2, NPOOL1);
    place_pack<<<(N_EDGES + 255) / 256, 256, 0, stream>>>(dst2, src2, edge_attr, deg2, fill2, pack2, N_EDGES);
    mlp_fused<128, 256, __hip_bfloat16><<<(NPOOL1 + 15) / 16, 256, 0, stream>>>(
        x2, NPOOL1, w2a, b2a, g2, be2, w2b, b2b, hm2);

    fill_f32<<<(NGRAPH * DIM + 255) / 256, 256, 0, stream>>>(gmax, NGRAPH * DIM, -INFINITY);
    gather2<<<(NPOOL1 * 64) / 256, 256, 0, stream>>>(hm2, deg2, offs2, cnt2, pack2, pb2, gmax);

    // ---- head ----
    head<<<NGRAPH, 128, 0, stream>>>(gmax, energy, emb_w, emb_b, emb_g, emb_be,
                                     lw1, lb1, lg, lbe, lw2, lb2, out);
}